// Round 6
// baseline (108.526 us; speedup 1.0000x reference)
//
#include <hip/hip_runtime.h>

// VectorQuantizer: N=65536 rows x D=64, K=1024 codes.
// argmin_k ||x - e_k||^2 == argmin_k ( ||e_k||^2 - 2 x.e_k )
// R6 (=R5 + vq_pack row-width fix): pre-packed bf16 codebook (pre-swizzled)
// in d_ws; main kernel stages 256-code chunks via global_load_lds (async DMA,
// no VALU), double-buffered with raw s_barrier. XOR-swizzled LDS, 128 B rows.

#define NROWS 65536
#define DDIM 64
#define KEMB 1024
#define KCHUNK 256
#define NCHUNKS (KEMB / KCHUNK)            // 4
#define BLKTHREADS 256                     // 4 waves
#define ROWS_PER_BLOCK 128                 // 32 rows/wave
#define NBLOCKS (NROWS / ROWS_PER_BLOCK)   // 512 -> 2 blocks/CU
#define CHUNK_BYTES (KCHUNK * 128)         // 32768
#define P_OFF 128                          // packed codebook offset in ws (bytes)
#define E2_OFF (P_OFF + KEMB * 128)        // ||e||^2 array offset (16B-aligned)

using bf16x8 = __attribute__((ext_vector_type(8))) short;
using f32x16 = __attribute__((ext_vector_type(16))) float;

__device__ __forceinline__ unsigned short f2bf(float f) {
    union { float f; unsigned u; } v; v.f = f;
    unsigned u = v.u;
    return (unsigned short)((u + 0x7FFFu + ((u >> 16) & 1u)) >> 16);  // RNE
}

__device__ __forceinline__ void gld16(const void* g, void* l) {
    __builtin_amdgcn_global_load_lds(
        (const __attribute__((address_space(1))) void*)g,
        (__attribute__((address_space(3))) void*)l, 16, 0, 0);
}

// ---- pre-pack: emb fp32 -> bf16, pre-swizzled so linear DMA == swizzled LDS.
// Target LDS layout: byte(r, b) = r*128 + (b ^ ((r&7)<<4)), i.e. 16B granule
// g' of P-row r holds source granule g' ^ (r&7).
// 8 threads per row (one 16B granule each), 32 rows per 256-thread block.
__global__ __launch_bounds__(256) void vq_pack(
    const float* __restrict__ emb, char* __restrict__ P, float* __restrict__ e2g)
{
    const int tid = threadIdx.x;
    const int lr = tid >> 3, cg = tid & 7;            // row-in-block, granule
    const int r = blockIdx.x * 32 + lr;
    const float4* emb4 = (const float4*)emb;
    const int q0 = r * 16 + ((cg * 2) ^ ((r & 7) << 1));   // src float4 idx (0..14 even)
    float4 v0 = emb4[q0];
    float4 v1 = emb4[q0 + 1];
    bf16x8 o;
    o[0] = (short)f2bf(v0.x); o[1] = (short)f2bf(v0.y);
    o[2] = (short)f2bf(v0.z); o[3] = (short)f2bf(v0.w);
    o[4] = (short)f2bf(v1.x); o[5] = (short)f2bf(v1.y);
    o[6] = (short)f2bf(v1.z); o[7] = (short)f2bf(v1.w);
    *(bf16x8*)&P[r * 128 + cg * 16] = o;
    float part = v0.x*v0.x + v0.y*v0.y + v0.z*v0.z + v0.w*v0.w
               + v1.x*v1.x + v1.y*v1.y + v1.z*v1.z + v1.w*v1.w;
    #pragma unroll
    for (int m = 4; m >= 1; m >>= 1) part += __shfl_xor(part, m);  // 8-lane group
    if (cg == 0) e2g[r] = part;
}

__global__ __launch_bounds__(BLKTHREADS) void vq_main(
    const float* __restrict__ lat, const float* __restrict__ emb,
    float* __restrict__ out, unsigned* __restrict__ ticket,
    float* __restrict__ lossacc, const char* __restrict__ P,
    const char* __restrict__ e2src)
{
    __shared__ __align__(16) short ebf[2][CHUNK_BYTES / 2];  // 2 x 32768 B
    __shared__ __align__(16) float e2f[KEMB];                // 4096 B
    __shared__ int   lbk[ROWS_PER_BLOCK];
    __shared__ float lloss[4];

    const int tid  = threadIdx.x;
    const int lane = tid & 63;
    const int w    = tid >> 6;      // wave 0..3
    const int lo   = lane & 31;
    const int hi   = lane >> 5;
    const int blk  = blockIdx.x;

    const float4* lat4 = (const float4*)lat;
    const float4* emb4 = (const float4*)emb;

    // ---- A fragments: this wave's 32 rows, D=64, in registers ----
    // 32x32x16 A layout: row = lane&31, k = (lane>>5)*8 + j; step s adds s*16
    const int rowg = blk * ROWS_PER_BLOCK + w * 32 + lo;
    bf16x8 afrag[4];
    #pragma unroll
    for (int s = 0; s < 4; ++s) {
        float4 f0 = lat4[rowg * 16 + s * 4 + hi * 2];
        float4 f1 = lat4[rowg * 16 + s * 4 + hi * 2 + 1];
        bf16x8 a;
        a[0] = (short)f2bf(f0.x); a[1] = (short)f2bf(f0.y);
        a[2] = (short)f2bf(f0.z); a[3] = (short)f2bf(f0.w);
        a[4] = (short)f2bf(f1.x); a[5] = (short)f2bf(f1.y);
        a[6] = (short)f2bf(f1.z); a[7] = (short)f2bf(f1.w);
        afrag[s] = a;
    }
    __builtin_amdgcn_sched_barrier(0);

    // ---- prologue DMA: e2 (1 inst/wave) + chunk0 (8 inst/wave) ----
    gld16(e2src + w * 1024 + lane * 16, (char*)e2f + w * 1024);
    {
        const char* src = P + (size_t)w * 8192 + lane * 16;
        char* dst = (char*)&ebf[0][0] + w * 8192;
        #pragma unroll
        for (int i = 0; i < 8; ++i) gld16(src + i * 1024, dst + i * 1024);
    }
    asm volatile("s_waitcnt vmcnt(0)" ::: "memory");
    __builtin_amdgcn_s_barrier();
    __builtin_amdgcn_sched_barrier(0);

    float best[16];
    int   bk[16];
    #pragma unroll
    for (int j = 0; j < 16; ++j) { best[j] = 3.0e38f; bk[j] = 0; }

    // swizzled B-read offsets (shorts): (s*16 + hi*8) ^ ((row&7)<<3), row≡lo (mod 8)
    int offs[4];
    #pragma unroll
    for (int s = 0; s < 4; ++s) offs[s] = (s * 16 + hi * 8) ^ ((lo & 7) << 3);

    #pragma unroll
    for (int c = 0; c < NCHUNKS; ++c) {
        const int cur = c & 1;
        if (c < NCHUNKS - 1) {   // stage next chunk into other buffer
            const char* src = P + (size_t)(c + 1) * CHUNK_BYTES + w * 8192 + lane * 16;
            char* dst = (char*)&ebf[cur ^ 1][0] + w * 8192;
            #pragma unroll
            for (int i = 0; i < 8; ++i) gld16(src + i * 1024, dst + i * 1024);
        }
        const short* eb = &ebf[cur][0];
        #pragma unroll 2
        for (int kt = 0; kt < KCHUNK / 32; ++kt) {
            const int kl = kt * 32 + lo;          // row in chunk
            f32x16 acc;
            #pragma unroll
            for (int j = 0; j < 16; ++j) acc[j] = 0.0f;
            #pragma unroll
            for (int s = 0; s < 4; ++s) {
                bf16x8 b = *(const bf16x8*)&eb[kl * 64 + offs[s]];
                acc = __builtin_amdgcn_mfma_f32_32x32x16_bf16(afrag[s], b, acc, 0, 0, 0);
            }
            const float e2v = e2f[c * KCHUNK + kl];
            const int   kg  = c * KCHUNK + kl;
            #pragma unroll
            for (int j = 0; j < 16; ++j) {
                float s = fmaf(-2.0f, acc[j], e2v);   // dist - ||x||^2
                bool u = s < best[j];
                best[j] = u ? s : best[j];
                bk[j]   = u ? kg : bk[j];
            }
        }
        if (c < NCHUNKS - 1) {
            asm volatile("s_waitcnt vmcnt(0)" ::: "memory");  // next chunk landed
            __builtin_amdgcn_s_barrier();                     // + everyone done reading
            __builtin_amdgcn_sched_barrier(0);
        }
    }

    // ---- cross-lane argmin over the 32 code-columns ----
    #pragma unroll
    for (int j = 0; j < 16; ++j) {
        float v = best[j]; int k = bk[j];
        #pragma unroll
        for (int m = 16; m >= 1; m >>= 1) {
            float ov = __shfl_xor(v, m);
            int   ok = __shfl_xor(k, m);
            bool t = (ov < v) || (ov == v && ok < k);  // first-index tiebreak
            v = t ? ov : v; k = t ? ok : k;
        }
        best[j] = v; bk[j] = k;
    }
    if (lo == 0) {
        // C/D layout: row = (reg&3) + 8*(reg>>2) + 4*hi
        #pragma unroll
        for (int j = 0; j < 16; ++j) {
            int rloc = (j & 3) + 8 * (j >> 2) + 4 * hi;
            lbk[w * 32 + rloc] = bk[j];
        }
    }
    __syncthreads();

    // ---- output: quantized_st = x + (q - x), loss partial ----
    float loss = 0.f;
    {
        const int row = tid >> 1, half = tid & 1;
        const int rg = blk * ROWS_PER_BLOCK + row;
        const int kb = lbk[row];
        float4* out4 = (float4*)out;
        #pragma unroll
        for (int j = 0; j < 8; ++j) {
            float4 x = lat4[rg * 16 + half * 8 + j];
            float4 q = emb4[kb * 16 + half * 8 + j];
            float dx = q.x - x.x, dy = q.y - x.y, dz = q.z - x.z, dw = q.w - x.w;
            float4 o;
            o.x = x.x + dx; o.y = x.y + dy; o.z = x.z + dz; o.w = x.w + dw;
            loss += dx*dx + dy*dy + dz*dz + dw*dw;
            out4[rg * 16 + half * 8 + j] = o;
        }
    }
    #pragma unroll
    for (int m = 32; m >= 1; m >>= 1) loss += __shfl_down(loss, m);
    if (lane == 0) lloss[w] = loss;
    __syncthreads();

    if (tid == 0) {
        float part = lloss[0] + lloss[1] + lloss[2] + lloss[3];
        float old = atomicAdd(lossacc, part);       // device-scope
        asm volatile("" :: "v"(old) : "memory");    // force completion first
        unsigned t = atomicAdd(ticket, 1u);
        if (t == NBLOCKS - 1) {                     // last block: all adds visible
            float tot = atomicAdd(lossacc, 0.0f);   // coherent read
            out[NROWS * DDIM] = tot * (1.25f / (float)(NROWS * DDIM));
        }
    }
}

extern "C" void kernel_launch(void* const* d_in, const int* in_sizes, int n_in,
                              void* d_out, int out_size, void* d_ws, size_t ws_size,
                              hipStream_t stream)
{
    const float* lat = (const float*)d_in[0];
    const float* emb = (const float*)d_in[1];
    float* out = (float*)d_out;
    unsigned* ticket = (unsigned*)d_ws;             // ws[0]
    float* lossacc = (float*)((char*)d_ws + 4);     // ws[4..8)
    char* P   = (char*)d_ws + P_OFF;                // packed swizzled bf16 codebook
    char* e2b = (char*)d_ws + E2_OFF;               // ||e||^2 (fp32, 4 KB)

    hipMemsetAsync(d_ws, 0, 8, stream);             // zero ticket + loss accum
    vq_pack<<<KEMB / 32, 256, 0, stream>>>(emb, P, (float*)e2b);
    vq_main<<<NBLOCKS, BLKTHREADS, 0, stream>>>(lat, emb, out, ticket, lossacc,
                                                (const char*)P, (const char*)e2b);
}